// Round 6
// baseline (70.552 us; speedup 1.0000x reference)
//
#include <hip/hip_runtime.h>

#define C2   2.8853900817779268f    //  2*log2(e)
#define NC2 -2.8853900817779268f    // -2*log2(e)

// Kernel 1: projection + exp precompute.
// Eq[b*512+q][h] = exp2(clamp(C2 * (queries @ Wq)[q][h], +-60)), Ek likewise (row-major).
__global__ __launch_bounds__(256) void proj_exp_kernel(
    const float* __restrict__ queries,
    const float* __restrict__ keys,
    const float* __restrict__ Wq,
    const float* __restrict__ Wk,
    float* __restrict__ Eq,
    float* __restrict__ Ek)
{
    __shared__ float w_lds[64 * 64];
    __shared__ float in_lds[256];

    const int t   = threadIdx.x;
    const int blk = blockIdx.x;          // 0..2047
    const int r0  = blk * 4;             // virtual row among 8192
    const bool isQ = (r0 < 4096);
    const float* __restrict__ W  = isQ ? Wq : Wk;
    const float* __restrict__ in = isQ ? queries : keys;
    float* __restrict__ Eo       = isQ ? Eq : Ek;
    const int rbase = isQ ? r0 : (r0 - 4096);

#pragma unroll
    for (int i = 0; i < 16; ++i)
        w_lds[t + i * 256] = W[t + i * 256];
    in_lds[t] = in[(size_t)rbase * 64 + t];
    __syncthreads();

    const int h  = t & 63;
    const int rl = t >> 6;               // 0..3 local row
    float acc = 0.f;
#pragma unroll
    for (int i = 0; i < 64; ++i)
        acc = fmaf(in_lds[rl * 64 + i], w_lds[i * 64 + h], acc);

    float x = fminf(fmaxf(acc * C2, -60.f), 60.f);  // bounded: products < 2^120
    Eo[(size_t)rbase * 64 + t] = __builtin_amdgcn_exp2f(x);
}

// Kernel 2: fused scores + softmax + PV, register-resident Ek, LDS-broadcast Eq/wv.
// Block = 8 waves x 64 lanes; lane l of wave w owns k = w*64+l (Ek row in 64 VGPRs)
// for 8 q-rows. Inner loop: ek in VGPRs, eq/wv via uniform-address ds_read_b128
// broadcasts (conflict-free, no SGPR pressure, no VMEM).
// score'[q][k] = -2 * sum_h wv[h] * rcp(1 + Eq[q][h]*Ek[k][h])   (softmax-invariant shift)
// p = exp2(score'*log2e) without max subtraction (|score'| <= 2*sum|wv| ~ 26, fp32-safe;
// masked k -> p = 0 exactly). Score and PV phases are wave-local.
__global__ __launch_bounds__(512, 4) void attn_kernel(
    const float* __restrict__ Eq,
    const float* __restrict__ Ek,
    const float* __restrict__ wv,
    const float* __restrict__ V,
    const int* __restrict__ valid_lens,
    float* __restrict__ out)
{
    __shared__ float p_lds[8][512];        // [q][k]
    __shared__ float part_lds[8 * 8 * 64]; // [w][q][d] PV partials
    __shared__ float wsum[8][8];           // [w][q] per-wave softmax partial sums
    __shared__ float eq_lds[8 * 64];       // the block's 8 Eq rows
    __shared__ float wv_lds[64];

    const int t   = threadIdx.x;
    const int bid = blockIdx.x;          // 0..511
    const int b   = bid >> 6;
    const int q0  = (bid & 63) << 3;
    const int l   = t & 63;
    const int w   = __builtin_amdgcn_readfirstlane(threadIdx.x >> 6);  // uniform wave id
    const int vl  = valid_lens[b];
    const int k   = w * 64 + l;
    const bool kvalid = (k < vl);

    // stage Eq rows + wv into LDS (coalesced, one-time)
    eq_lds[t] = Eq[(size_t)(b * 512 + q0) * 64 + t];
    if (t < 64) wv_lds[t] = wv[t];

    // ---- lane-resident Ek row: 64 VGPRs, loaded once (L2-resident)
    float ek[64];
    {
        const float4* ekr = reinterpret_cast<const float4*>(Ek + (size_t)(b * 512 + k) * 64);
#pragma unroll
        for (int i = 0; i < 16; ++i) {
            float4 v = ekr[i];
            ek[4 * i + 0] = v.x; ek[4 * i + 1] = v.y;
            ek[4 * i + 2] = v.z; ek[4 * i + 3] = v.w;
        }
    }
    __syncthreads();                     // eq_lds/wv_lds ready

    // ---- score + softmax numerators: pure VALU/trans + uniform LDS broadcasts
#pragma unroll 1
    for (int q = 0; q < 8; ++q) {
        const float* eql = &eq_lds[q * 64];
        float a0 = 0.f, a1 = 0.f, a2 = 0.f, a3 = 0.f;
#pragma unroll
        for (int h = 0; h < 64; h += 8) {
            float4 e0 = *reinterpret_cast<const float4*>(eql + h);       // uniform b128 broadcast
            float4 e1 = *reinterpret_cast<const float4*>(eql + h + 4);
            float4 w0 = *reinterpret_cast<const float4*>(wv_lds + h);
            float4 w1 = *reinterpret_cast<const float4*>(wv_lds + h + 4);
            a0 = fmaf(w0.x, __builtin_amdgcn_rcpf(fmaf(e0.x, ek[h + 0], 1.f)), a0);
            a1 = fmaf(w0.y, __builtin_amdgcn_rcpf(fmaf(e0.y, ek[h + 1], 1.f)), a1);
            a2 = fmaf(w0.z, __builtin_amdgcn_rcpf(fmaf(e0.z, ek[h + 2], 1.f)), a2);
            a3 = fmaf(w0.w, __builtin_amdgcn_rcpf(fmaf(e0.w, ek[h + 3], 1.f)), a3);
            a0 = fmaf(w1.x, __builtin_amdgcn_rcpf(fmaf(e1.x, ek[h + 4], 1.f)), a0);
            a1 = fmaf(w1.y, __builtin_amdgcn_rcpf(fmaf(e1.y, ek[h + 5], 1.f)), a1);
            a2 = fmaf(w1.z, __builtin_amdgcn_rcpf(fmaf(e1.z, ek[h + 6], 1.f)), a2);
            a3 = fmaf(w1.w, __builtin_amdgcn_rcpf(fmaf(e1.w, ek[h + 7], 1.f)), a3);
        }
        float p = kvalid ? __builtin_amdgcn_exp2f(((a0 + a1) + (a2 + a3)) * NC2) : 0.f;
        p_lds[q][k] = p;                 // consecutive lanes: conflict-free b32
        float ps = p;
#pragma unroll
        for (int off = 32; off > 0; off >>= 1) ps += __shfl_xor(ps, off);
        if (l == 0) wsum[w][q] = ps;
    }

    // ---- PV: wave w consumes ONLY its own k-chunk's p (self-written -> no barrier).
    // lane = d column; each V row read exactly once per block (coalesced, L2-resident).
    const float* __restrict__ Vb = V + (size_t)b * 512 * 64;
    float acc[8] = {0.f, 0.f, 0.f, 0.f, 0.f, 0.f, 0.f, 0.f};
    const int kb = w * 64;
#pragma unroll 4
    for (int kk = 0; kk < 64; kk += 4) {
        const int k0 = kb + kk;
        float4 pq[8];
#pragma unroll
        for (int q = 0; q < 8; ++q)
            pq[q] = *reinterpret_cast<const float4*>(&p_lds[q][k0]);   // uniform broadcast b128
        float v0 = Vb[(size_t)(k0 + 0) * 64 + l];
        float v1 = Vb[(size_t)(k0 + 1) * 64 + l];
        float v2 = Vb[(size_t)(k0 + 2) * 64 + l];
        float v3 = Vb[(size_t)(k0 + 3) * 64 + l];
#pragma unroll
        for (int q = 0; q < 8; ++q) {
            acc[q] = fmaf(pq[q].x, v0, acc[q]);
            acc[q] = fmaf(pq[q].y, v1, acc[q]);
            acc[q] = fmaf(pq[q].z, v2, acc[q]);
            acc[q] = fmaf(pq[q].w, v3, acc[q]);
        }
    }
#pragma unroll
    for (int q = 0; q < 8; ++q)
        part_lds[(w * 8 + q) * 64 + l] = acc[q];
    __syncthreads();

    // ---- combine: wave w owns output q-row w, lane = d
    float denom = 0.f, o = 0.f;
#pragma unroll
    for (int ww = 0; ww < 8; ++ww) {
        denom += wsum[ww][w];                         // uniform broadcast
        o     += part_lds[(ww * 8 + w) * 64 + l];     // consecutive lanes
    }
    out[(size_t)(b * 512 + q0 + w) * 64 + l] = o * __builtin_amdgcn_rcpf(denom);
}

extern "C" void kernel_launch(void* const* d_in, const int* in_sizes, int n_in,
                              void* d_out, int out_size, void* d_ws, size_t ws_size,
                              hipStream_t stream) {
    (void)in_sizes; (void)n_in; (void)out_size; (void)ws_size;
    const float* queries = (const float*)d_in[0];
    const float* keys    = (const float*)d_in[1];
    const float* values  = (const float*)d_in[2];
    const int*   vlens   = (const int*)d_in[3];
    const float* Wq      = (const float*)d_in[4];
    const float* Wk      = (const float*)d_in[5];
    const float* wv      = (const float*)d_in[6];
    float* out = (float*)d_out;

    float* Eq = (float*)d_ws;                 // 8*512*64 floats = 1 MB
    float* Ek = Eq + 8 * 512 * 64;            // 1 MB

    proj_exp_kernel<<<2048, 256, 0, stream>>>(queries, keys, Wq, Wk, Eq, Ek);
    attn_kernel<<<512, 512, 0, stream>>>(Eq, Ek, wv, values, vlens, out);
}

// Round 7
// 40.297 us; speedup vs baseline: 1.7508x; 1.7508x over previous
//
#include <hip/hip_runtime.h>

#define C2   2.8853900817779268f    //  2*log2(e)
#define NC2 -2.8853900817779268f    // -2*log2(e)

// Kernel 1: projection + exp precompute.
// Eq[b*512+q][h] = exp2(clamp(C2 * (queries @ Wq)[q][h], +-60)), Ek likewise (row-major).
__global__ __launch_bounds__(256) void proj_exp_kernel(
    const float* __restrict__ queries,
    const float* __restrict__ keys,
    const float* __restrict__ Wq,
    const float* __restrict__ Wk,
    float* __restrict__ Eq,
    float* __restrict__ Ek)
{
    __shared__ float w_lds[64 * 64];
    __shared__ float in_lds[256];

    const int t   = threadIdx.x;
    const int blk = blockIdx.x;          // 0..2047
    const int r0  = blk * 4;             // virtual row among 8192
    const bool isQ = (r0 < 4096);
    const float* __restrict__ W  = isQ ? Wq : Wk;
    const float* __restrict__ in = isQ ? queries : keys;
    float* __restrict__ Eo       = isQ ? Eq : Ek;
    const int rbase = isQ ? r0 : (r0 - 4096);

#pragma unroll
    for (int i = 0; i < 16; ++i)
        w_lds[t + i * 256] = W[t + i * 256];
    in_lds[t] = in[(size_t)rbase * 64 + t];
    __syncthreads();

    const int h  = t & 63;
    const int rl = t >> 6;               // 0..3 local row
    float acc = 0.f;
#pragma unroll
    for (int i = 0; i < 64; ++i)
        acc = fmaf(in_lds[rl * 64 + i], w_lds[i * 64 + h], acc);

    float x = fminf(fmaxf(acc * C2, -60.f), 60.f);  // bounded: products < 2^120
    Eo[(size_t)rbase * 64 + t] = __builtin_amdgcn_exp2f(x);
}

// Kernel 2: fused scores + softmax + PV. h-split register-resident Ek.
// Block = 8 waves x 64 lanes, 4 q-rows; grid = 1024.
// Lane pair (l, l^32) of wave w shares k = c*256 + w*32 + (l&31); lane holds
// ONLY its 32-element h-half of the Ek row (32 VGPRs -> no spill at 64-VGPR
// occupancy). Per-half partial scores combine with one __shfl_xor(s,32)
// (commutative add -> both lanes get identical p).
// score'[q][k] = -2 * sum_h wv[h] * rcp(1 + Eq[q][h]*Ek[k][h])  (softmax-shift-invariant)
// p = exp2(score'*log2e) without max subtraction (|score'| <= 2*sum|wv| ~ 26, fp32-safe;
// masked k -> p = 0 exactly). Score and PV are wave-local: p is re-read only by
// the wave that wrote it -> no barrier between score and PV.
__global__ __launch_bounds__(512, 4) void attn_kernel(
    const float* __restrict__ Eq,
    const float* __restrict__ Ek,
    const float* __restrict__ wv,
    const float* __restrict__ V,
    const int* __restrict__ valid_lens,
    float* __restrict__ out)
{
    __shared__ float p_lds[4][512];        // [q][k]
    __shared__ float part_lds[8][4][64];   // [w][q][d] PV partials
    __shared__ float wsum[2][8][4];        // [chunk][w][q] softmax partial sums
    __shared__ float eq_lds[4 * 64];       // the block's 4 Eq rows
    __shared__ float wv_lds[64];

    const int t   = threadIdx.x;
    const int bid = blockIdx.x;          // 0..1023
    const int b   = bid >> 7;
    const int q0  = (bid & 127) << 2;
    const int l   = t & 63;
    const int w   = __builtin_amdgcn_readfirstlane(threadIdx.x >> 6);  // uniform wave id
    const int vl  = valid_lens[b];
    const int lk  = l & 31;              // k sub-index within wave
    const int hb  = (l >> 5) << 5;       // h-half base: 0 or 32

    // stage Eq rows + wv into LDS (one-time)
    if (t < 256)              eq_lds[t]       = Eq[(size_t)(b * 512 + q0) * 64 + t];
    else if (t < 320)         wv_lds[t - 256] = wv[t - 256];
    __syncthreads();

#pragma unroll 1
    for (int c = 0; c < 2; ++c) {
        const int k = c * 256 + w * 32 + lk;
        const bool kvalid = (k < vl);

        // lane-resident Ek half-row: 32 VGPRs (L2-resident load, 128B/lane)
        float ek[32];
        {
            const float4* ekr = reinterpret_cast<const float4*>(
                Ek + (size_t)(b * 512 + k) * 64 + hb);
#pragma unroll
            for (int i = 0; i < 8; ++i) {
                float4 v = ekr[i];
                ek[4 * i + 0] = v.x; ek[4 * i + 1] = v.y;
                ek[4 * i + 2] = v.z; ek[4 * i + 3] = v.w;
            }
        }

#pragma unroll 1
        for (int q = 0; q < 4; ++q) {
            const float* eql = &eq_lds[q * 64 + hb];
            const float* wvl = &wv_lds[hb];
            float a0 = 0.f, a1 = 0.f, a2 = 0.f, a3 = 0.f;
#pragma unroll
            for (int h = 0; h < 32; h += 8) {
                float4 e0 = *reinterpret_cast<const float4*>(eql + h);      // uniform b128
                float4 e1 = *reinterpret_cast<const float4*>(eql + h + 4);
                float4 w0 = *reinterpret_cast<const float4*>(wvl + h);
                float4 w1 = *reinterpret_cast<const float4*>(wvl + h + 4);
                a0 = fmaf(w0.x, __builtin_amdgcn_rcpf(fmaf(e0.x, ek[h + 0], 1.f)), a0);
                a1 = fmaf(w0.y, __builtin_amdgcn_rcpf(fmaf(e0.y, ek[h + 1], 1.f)), a1);
                a2 = fmaf(w0.z, __builtin_amdgcn_rcpf(fmaf(e0.z, ek[h + 2], 1.f)), a2);
                a3 = fmaf(w0.w, __builtin_amdgcn_rcpf(fmaf(e0.w, ek[h + 3], 1.f)), a3);
                a0 = fmaf(w1.x, __builtin_amdgcn_rcpf(fmaf(e1.x, ek[h + 4], 1.f)), a0);
                a1 = fmaf(w1.y, __builtin_amdgcn_rcpf(fmaf(e1.y, ek[h + 5], 1.f)), a1);
                a2 = fmaf(w1.z, __builtin_amdgcn_rcpf(fmaf(e1.z, ek[h + 6], 1.f)), a2);
                a3 = fmaf(w1.w, __builtin_amdgcn_rcpf(fmaf(e1.w, ek[h + 7], 1.f)), a3);
            }
            float s = (a0 + a1) + (a2 + a3);
            s += __shfl_xor(s, 32);              // combine h-halves; both lanes identical
            float p = kvalid ? __builtin_amdgcn_exp2f(s * NC2) : 0.f;
            if (l < 32) p_lds[q][k] = p;         // half-wave, consecutive: conflict-free
            float ps = p;
#pragma unroll
            for (int off = 16; off > 0; off >>= 1)
                ps += __shfl_xor(ps, off);       // sum within each 32-half = true chunk sum
            if (l == 0) wsum[c][w][q] = ps;
        }
    }

    // ---- PV: wave w consumes ONLY p it wrote (k = c*256 + w*32 + 0..31) -> no barrier.
    // lane = d column; each V row read exactly once per block (coalesced, L2-resident).
    const float* __restrict__ Vb = V + (size_t)b * 512 * 64;
    float acc[4] = {0.f, 0.f, 0.f, 0.f};
#pragma unroll
    for (int c = 0; c < 2; ++c) {
        const int kb = c * 256 + w * 32;
#pragma unroll 2
        for (int kk = 0; kk < 32; kk += 4) {
            const int k0 = kb + kk;
            float4 pq[4];
#pragma unroll
            for (int q = 0; q < 4; ++q)
                pq[q] = *reinterpret_cast<const float4*>(&p_lds[q][k0]);  // uniform b128
            float v0 = Vb[(size_t)(k0 + 0) * 64 + l];
            float v1 = Vb[(size_t)(k0 + 1) * 64 + l];
            float v2 = Vb[(size_t)(k0 + 2) * 64 + l];
            float v3 = Vb[(size_t)(k0 + 3) * 64 + l];
#pragma unroll
            for (int q = 0; q < 4; ++q) {
                acc[q] = fmaf(pq[q].x, v0, acc[q]);
                acc[q] = fmaf(pq[q].y, v1, acc[q]);
                acc[q] = fmaf(pq[q].z, v2, acc[q]);
                acc[q] = fmaf(pq[q].w, v3, acc[q]);
            }
        }
    }
#pragma unroll
    for (int q = 0; q < 4; ++q)
        part_lds[w][q][l] = acc[q];
    __syncthreads();

    // ---- combine: waves 0..3 own q-row w, lane = d
    if (w < 4) {
        const int q = w;
        float denom = 0.f;
#pragma unroll
        for (int c = 0; c < 2; ++c)
#pragma unroll
            for (int ww = 0; ww < 8; ++ww)
                denom += wsum[c][ww][q];                  // uniform reads
        float o = 0.f;
#pragma unroll
        for (int ww = 0; ww < 8; ++ww)
            o += part_lds[ww][q][l];                      // consecutive lanes
        out[(size_t)(b * 512 + q0 + q) * 64 + l] = o * __builtin_amdgcn_rcpf(denom);
    }
}

extern "C" void kernel_launch(void* const* d_in, const int* in_sizes, int n_in,
                              void* d_out, int out_size, void* d_ws, size_t ws_size,
                              hipStream_t stream) {
    (void)in_sizes; (void)n_in; (void)out_size; (void)ws_size;
    const float* queries = (const float*)d_in[0];
    const float* keys    = (const float*)d_in[1];
    const float* values  = (const float*)d_in[2];
    const int*   vlens   = (const int*)d_in[3];
    const float* Wq      = (const float*)d_in[4];
    const float* Wk      = (const float*)d_in[5];
    const float* wv      = (const float*)d_in[6];
    float* out = (float*)d_out;

    float* Eq = (float*)d_ws;                 // 8*512*64 floats = 1 MB
    float* Ek = Eq + 8 * 512 * 64;            // 1 MB

    proj_exp_kernel<<<2048, 256, 0, stream>>>(queries, keys, Wq, Wk, Eq, Ek);
    attn_kernel<<<1024, 512, 0, stream>>>(Eq, Ek, wv, values, vlens, out);
}